// Round 14
// baseline (29717.953 us; speedup 1.0000x reference)
//
#include <hip/hip_runtime.h>
#include <hip/hip_fp16.h>

#define TLEN 16384
#define HD 128

typedef _Float16 v8h __attribute__((ext_vector_type(8)));
typedef float    v4f __attribute__((ext_vector_type(4)));

union U4H8 { uint4 u; v8h h; };

__device__ __forceinline__ v8h cvt8(const float* p) {
    v8h r;
    #pragma unroll
    for (int i = 0; i < 8; ++i) r[i] = (_Float16)p[i];
    return r;
}
__device__ __forceinline__ unsigned int packh2(float a, float b) {
    union { _Float16 h[2]; unsigned int u; } c;
    c.h[0] = (_Float16)a; c.h[1] = (_Float16)b; return c.u;
}
__device__ __forceinline__ float selg(v4f a, int g) {
    const float lo = (g & 1) ? a.y : a.x;
    const float hi = (g & 1) ? a.w : a.z;
    return (g & 2) ? hi : lo;
}
#define PINA(x) asm volatile("" : "+a"(x))

// ---------------------------------------------------------------------------
// R14 = R12 (best, 11.1ms) + critical-path VALU/LDS plumbing cuts.
// R12 counters: per-CU VALU ~1060 cyc/step SERIAL with MFMA ~620 -> step 1600.
// Cuts: (1) h2L+hringL unified into one 32-slot history (write h_t to slot
// t&31; step t reads slot (t-1)&31) => ONE ds_write/lane/step; (2) 4 helper
// waves (768 thr) own the hs flush => compute waves never carry the 16-step
// LDS-read+global-store spike; (3) compute waves byte-identical to R12:
// 8 waves, wave w owns gate-rows 16w..16w+15 (r,z,n x {Whh,Wih}), 24 AGPR-
// pinned A-frags, biases as C-init (n-gate bih separate scalar — outside the
// r-multiply), ux steps: 3 Wc-MFMAs (folded embed, 1.0-pad carries bemb),
// in-register gates, ONE barrier/step.
// ---------------------------------------------------------------------------
__global__
__attribute__((amdgpu_flat_work_group_size(768, 768)))
void gru_kernel(
    const float* __restrict__ px,
    const float* __restrict__ py,
    const float* __restrict__ vx,
    const float* __restrict__ vy,
    const float* __restrict__ Wemb,   // [128,4]
    const float* __restrict__ bemb,   // [128]
    const float* __restrict__ Wih,    // [384,128]
    const float* __restrict__ Whh,    // [384,128]
    const float* __restrict__ bih,    // [384]
    const float* __restrict__ bhh,    // [384]
    const int*   __restrict__ step_mask, // [16384]
    const int*   __restrict__ ctxp,      // [1]
    unsigned short* __restrict__ hs)     // [4*16384*128] f16-bits staging
{
    const int tid  = threadIdx.x;
    const int w    = tid >> 6;          // wave 0..11 (0-7 compute, 8-11 helper)
    const int isC  = (w < 8);
    const int lane = tid & 63;
    const int m    = lane & 15;
    const int q8   = (lane >> 4) * 8;
    const int qq4  = (lane >> 4) * 4;
    const int cme  = lane & 3;
    const int gme  = (lane >> 2) & 3;
    const int kme  = 16 * (w & 7) + qq4 + gme;

    // unified h history + state: slot t&31 holds h AFTER step t (= hs[t]).
    __shared__ alignas(16) _Float16 hringL[32][4][160];  // padded c-stride
    __shared__ alignas(16) uint4 xpadL[256][4];          // [x0..x3,1,0,0,0] f16
    __shared__ int   uxbuf[256];
    __shared__ float WembL[512];
    __shared__ float bembL[128];
    __shared__ alignas(16) float Wc4[384][4];
    __shared__ float bfoldL[384];                        // Wih·bemb (no bih)

    // ---- A-frags: 6 tiles x 4 K-frags (compute waves; garbage on helpers) --
    const int wm = w & 7;
    v8h ahr0, ahr1, ahr2, ahr3, ahz0, ahz1, ahz2, ahz3, ahn0, ahn1, ahn2, ahn3;
    v8h air0, air1, air2, air3, aiz0, aiz1, aiz2, aiz3, ain0, ain1, ain2, ain3;
    {
        const float* pr = Whh + (size_t)(      16 * wm + m) * 128 + q8;
        const float* pz = Whh + (size_t)(128 + 16 * wm + m) * 128 + q8;
        const float* pn = Whh + (size_t)(256 + 16 * wm + m) * 128 + q8;
        ahr0 = cvt8(pr); ahr1 = cvt8(pr + 32); ahr2 = cvt8(pr + 64); ahr3 = cvt8(pr + 96);
        ahz0 = cvt8(pz); ahz1 = cvt8(pz + 32); ahz2 = cvt8(pz + 64); ahz3 = cvt8(pz + 96);
        ahn0 = cvt8(pn); ahn1 = cvt8(pn + 32); ahn2 = cvt8(pn + 64); ahn3 = cvt8(pn + 96);
        const float* qr = Wih + (size_t)(      16 * wm + m) * 128 + q8;
        const float* qz = Wih + (size_t)(128 + 16 * wm + m) * 128 + q8;
        const float* qn = Wih + (size_t)(256 + 16 * wm + m) * 128 + q8;
        air0 = cvt8(qr); air1 = cvt8(qr + 32); air2 = cvt8(qr + 64); air3 = cvt8(qr + 96);
        aiz0 = cvt8(qz); aiz1 = cvt8(qz + 32); aiz2 = cvt8(qz + 64); aiz3 = cvt8(qz + 96);
        ain0 = cvt8(qn); ain1 = cvt8(qn + 32); ain2 = cvt8(qn + 64); ain3 = cvt8(qn + 96);
    }
    PINA(ahr0); PINA(ahr1); PINA(ahr2); PINA(ahr3);
    PINA(ahz0); PINA(ahz1); PINA(ahz2); PINA(ahz3);
    PINA(ahn0); PINA(ahn1); PINA(ahn2); PINA(ahn3);
    PINA(air0); PINA(air1); PINA(air2); PINA(air3);
    PINA(aiz0); PINA(aiz1); PINA(aiz2); PINA(aiz3);
    PINA(ain0); PINA(ain1); PINA(ain2); PINA(ain3);

    // biases as C-init (r,z,n of hh; r,z,n of ih)
    const int rB = 16 * wm + qq4;
    const v4f bHR = { bhh[rB],       bhh[rB + 1],       bhh[rB + 2],       bhh[rB + 3] };
    const v4f bHZ = { bhh[128 + rB], bhh[128 + rB + 1], bhh[128 + rB + 2], bhh[128 + rB + 3] };
    const v4f bHN = { bhh[256 + rB], bhh[256 + rB + 1], bhh[256 + rB + 2], bhh[256 + rB + 3] };
    const v4f bIR = { bih[rB],       bih[rB + 1],       bih[rB + 2],       bih[rB + 3] };
    const v4f bIZ = { bih[128 + rB], bih[128 + rB + 1], bih[128 + rB + 2], bih[128 + rB + 3] };
    const v4f bIN = { bih[256 + rB], bih[256 + rB + 1], bih[256 + rB + 2], bih[256 + rB + 3] };

    if (tid < 512) WembL[tid] = Wemb[tid];
    if (tid < 128) bembL[tid] = bemb[tid];
    for (int i = tid; i < 32 * 4 * 160; i += 768) ((_Float16*)hringL)[i] = (_Float16)0.f;
    __syncthreads();
    // folded embed: Wc[g] = Wih[g]·Wemb, bfold[g] = Wih[g]·bemb  (NO bih)
    if (tid < 384) {
        const float* wr = Wih + (size_t)tid * 128;
        float c0 = 0.f, c1 = 0.f, c2 = 0.f, c3 = 0.f, cb = 0.f;
        #pragma unroll 4
        for (int j = 0; j < 128; ++j) {
            const float wv = wr[j];
            const float4 e = *(const float4*)&WembL[j * 4];
            c0 = fmaf(wv, e.x, c0); c1 = fmaf(wv, e.y, c1);
            c2 = fmaf(wv, e.z, c2); c3 = fmaf(wv, e.w, c3);
            cb = fmaf(wv, bembL[j], cb);
        }
        Wc4[tid][0] = c0; Wc4[tid][1] = c1; Wc4[tid][2] = c2; Wc4[tid][3] = c3;
        bfoldL[tid] = cb;
    }
    __syncthreads();
    // Wc A-frags: k=0..3 = Wc row, k=4 = bemb-fold, rest 0; lanes q8!=0 zero
    v8h wcr = {}, wcz = {}, wcn = {};
    if (isC && lane < 16) {
        wcr[0] = (_Float16)Wc4[      16*wm + m][0]; wcr[1] = (_Float16)Wc4[      16*wm + m][1];
        wcr[2] = (_Float16)Wc4[      16*wm + m][2]; wcr[3] = (_Float16)Wc4[      16*wm + m][3];
        wcr[4] = (_Float16)bfoldL[      16*wm + m];
        wcz[0] = (_Float16)Wc4[128 + 16*wm + m][0]; wcz[1] = (_Float16)Wc4[128 + 16*wm + m][1];
        wcz[2] = (_Float16)Wc4[128 + 16*wm + m][2]; wcz[3] = (_Float16)Wc4[128 + 16*wm + m][3];
        wcz[4] = (_Float16)bfoldL[128 + 16*wm + m];
        wcn[0] = (_Float16)Wc4[256 + 16*wm + m][0]; wcn[1] = (_Float16)Wc4[256 + 16*wm + m][1];
        wcn[2] = (_Float16)Wc4[256 + 16*wm + m][2]; wcn[3] = (_Float16)Wc4[256 + 16*wm + m][3];
        wcn[4] = (_Float16)bfoldL[256 + 16*wm + m];
    }
    PINA(wcr); PINA(wcz); PINA(wcn);

    const int ctxm = (ctxp[0] < 1) ? 1 : ctxp[0];
    float hold1 = 0.f;

    for (int t0 = 0; t0 < TLEN; t0 += 256) {
        for (int i = tid; i < 1024; i += 768) {
            const int t = i >> 2, c = i & 3;
            const int gt = t0 + t;
            const float* xa = (c == 0) ? px : (c == 1) ? py : (c == 2) ? vx : vy;
            uint4 u;
            u.x = packh2(xa[gt],            xa[TLEN + gt]);
            u.y = packh2(xa[2 * TLEN + gt], xa[3 * TLEN + gt]);
            u.z = packh2(1.f, 0.f);
            u.w = 0u;
            xpadL[t][c] = u;
        }
        if (tid < 256) {
            const int gt = t0 + tid;
            uxbuf[tid] = ((gt < ctxm) || (step_mask[gt] == 0)) ? 1 : 0;
        }
        __syncthreads();
        for (int tt = 0; tt < 256; ++tt) {
            const int gt  = t0 + tt;
            const int ux  = __builtin_amdgcn_readfirstlane(uxbuf[tt]);
            if (isC) {
                // B-frags from history slot (gt-1)&31 (h entering step gt)
                const uint4* hq = (const uint4*)&hringL[(gt + 31) & 31][cme][0];
                U4H8 b0, b1, b2, b3;
                b0.u = hq[ 0 + (lane >> 4)];
                b1.u = hq[ 4 + (lane >> 4)];
                b2.u = hq[ 8 + (lane >> 4)];
                b3.u = hq[12 + (lane >> 4)];
                v4f aHR = __builtin_amdgcn_mfma_f32_16x16x32_f16(ahr0, b0.h, bHR, 0, 0, 0);
                aHR     = __builtin_amdgcn_mfma_f32_16x16x32_f16(ahr1, b1.h, aHR, 0, 0, 0);
                aHR     = __builtin_amdgcn_mfma_f32_16x16x32_f16(ahr2, b2.h, aHR, 0, 0, 0);
                aHR     = __builtin_amdgcn_mfma_f32_16x16x32_f16(ahr3, b3.h, aHR, 0, 0, 0);
                v4f aHZ = __builtin_amdgcn_mfma_f32_16x16x32_f16(ahz0, b0.h, bHZ, 0, 0, 0);
                aHZ     = __builtin_amdgcn_mfma_f32_16x16x32_f16(ahz1, b1.h, aHZ, 0, 0, 0);
                aHZ     = __builtin_amdgcn_mfma_f32_16x16x32_f16(ahz2, b2.h, aHZ, 0, 0, 0);
                aHZ     = __builtin_amdgcn_mfma_f32_16x16x32_f16(ahz3, b3.h, aHZ, 0, 0, 0);
                v4f aHN = __builtin_amdgcn_mfma_f32_16x16x32_f16(ahn0, b0.h, bHN, 0, 0, 0);
                aHN     = __builtin_amdgcn_mfma_f32_16x16x32_f16(ahn1, b1.h, aHN, 0, 0, 0);
                aHN     = __builtin_amdgcn_mfma_f32_16x16x32_f16(ahn2, b2.h, aHN, 0, 0, 0);
                aHN     = __builtin_amdgcn_mfma_f32_16x16x32_f16(ahn3, b3.h, aHN, 0, 0, 0);
                v4f aIR, aIZ, aIN;
                if (!ux) {
                    aIR = __builtin_amdgcn_mfma_f32_16x16x32_f16(air0, b0.h, bIR, 0, 0, 0);
                    aIR = __builtin_amdgcn_mfma_f32_16x16x32_f16(air1, b1.h, aIR, 0, 0, 0);
                    aIR = __builtin_amdgcn_mfma_f32_16x16x32_f16(air2, b2.h, aIR, 0, 0, 0);
                    aIR = __builtin_amdgcn_mfma_f32_16x16x32_f16(air3, b3.h, aIR, 0, 0, 0);
                    aIZ = __builtin_amdgcn_mfma_f32_16x16x32_f16(aiz0, b0.h, bIZ, 0, 0, 0);
                    aIZ = __builtin_amdgcn_mfma_f32_16x16x32_f16(aiz1, b1.h, aIZ, 0, 0, 0);
                    aIZ = __builtin_amdgcn_mfma_f32_16x16x32_f16(aiz2, b2.h, aIZ, 0, 0, 0);
                    aIZ = __builtin_amdgcn_mfma_f32_16x16x32_f16(aiz3, b3.h, aIZ, 0, 0, 0);
                    aIN = __builtin_amdgcn_mfma_f32_16x16x32_f16(ain0, b0.h, bIN, 0, 0, 0);
                    aIN = __builtin_amdgcn_mfma_f32_16x16x32_f16(ain1, b1.h, aIN, 0, 0, 0);
                    aIN = __builtin_amdgcn_mfma_f32_16x16x32_f16(ain2, b2.h, aIN, 0, 0, 0);
                    aIN = __builtin_amdgcn_mfma_f32_16x16x32_f16(ain3, b3.h, aIN, 0, 0, 0);
                } else {
                    U4H8 xb;
                    xb.u = xpadL[tt][cme];
                    if (lane >= 16) { xb.u.x = 0u; xb.u.y = 0u; xb.u.z = 0u; xb.u.w = 0u; }
                    aIR = __builtin_amdgcn_mfma_f32_16x16x32_f16(wcr, xb.h, bIR, 0, 0, 0);
                    aIZ = __builtin_amdgcn_mfma_f32_16x16x32_f16(wcz, xb.h, bIZ, 0, 0, 0);
                    aIN = __builtin_amdgcn_mfma_f32_16x16x32_f16(wcn, xb.h, bIN, 0, 0, 0);
                }
                const float gir = selg(aIR, gme), ghr = selg(aHR, gme);
                const float giz = selg(aIZ, gme), ghz = selg(aHZ, gme);
                const float gin = selg(aIN, gme), ghn = selg(aHN, gme);
                const float r    = 1.f / (1.f + __expf(-(gir + ghr)));
                const float z    = 1.f / (1.f + __expf(-(giz + ghz)));
                const float npre = fmaf(r, ghn, gin);
                const float e2   = __expf(2.f * npre);
                const float n    = 1.f - 2.f / (e2 + 1.f);       // tanh
                const float hnew = fmaf(z, hold1 - n, n);        // (1-z)n + z h
                hold1 = hnew;
                hringL[gt & 31][cme][kme] = (_Float16)hnew;      // single write
            } else if ((gt & 15) == 1 && gt > 16) {
                // helpers: flush completed 16-step group (disjoint ring half)
                const int u = tid - 512;
                const int G = (gt >> 4) - 1;
                #pragma unroll
                for (int j = 0; j < 4; ++j) {
                    const int v  = u + (j << 8);
                    const int c  = v >> 8, sl = (v >> 4) & 15, g = v & 15;
                    ((uint4*)hs)[(size_t)(c * TLEN + (G << 4) + sl) * 16 + g] =
                        *(const uint4*)&hringL[((G & 1) << 4) + sl][c][g << 3];
                }
            }
            __syncthreads();
        }
    }
    // final flush: steps 16368..16383 (slots 16..31)
    if (tid < 256) {
        #pragma unroll
        for (int j = 0; j < 4; ++j) {
            const int v  = tid + (j << 8);
            const int c  = v >> 8, sl = (v >> 4) & 15, g = v & 15;
            ((uint4*)hs)[(size_t)(c * TLEN + 16368 + sl) * 16 + g] =
                *(const uint4*)&hringL[16 + sl][c][g << 3];
        }
    }
}

// ---------------------------------------------------------------------------
// Head MLP over all 65536 hidden states (unchanged).
// ---------------------------------------------------------------------------
__global__ __launch_bounds__(64) void head_kernel(
    const float*  __restrict__ W1,
    const float*  __restrict__ b1,
    const float*  __restrict__ W2,
    const float*  __restrict__ b2,
    const float*  __restrict__ W3,
    const float*  __restrict__ b3,
    const __half* __restrict__ hs,
    float*        __restrict__ out)
{
    __shared__ float W1L[64 * 128];
    __shared__ float W2L[64 * 64];
    __shared__ float W3L[2 * 64];
    __shared__ float b1L[64], b2L[64], b3L[2];
    __shared__ float y1L[64 * 65];

    const int tid = threadIdx.x;
    {
        float4* dst1 = (float4*)W1L; const float4* src1 = (const float4*)W1;
        for (int i = tid; i < 2048; i += 64) dst1[i] = src1[i];
        float4* dst2 = (float4*)W2L; const float4* src2 = (const float4*)W2;
        for (int i = tid; i < 1024; i += 64) dst2[i] = src2[i];
        if (tid < 32) ((float4*)W3L)[tid] = ((const float4*)W3)[tid];
        b1L[tid] = b1[tid];
        b2L[tid] = b2[tid];
        if (tid < 2) b3L[tid] = b3[tid];
    }
    __syncthreads();

    const int row = blockIdx.x * 64 + tid;
    float h[128];
    {
        const uint4* hp = (const uint4*)(hs + (size_t)row * HD);
        #pragma unroll
        for (int c = 0; c < 16; ++c) {
            uint4 q = hp[c];
            const __half2* hh = (const __half2*)&q;
            #pragma unroll
            for (int d = 0; d < 4; ++d) {
                const float2 f = __half22float2(hh[d]);
                h[c*8 + d*2 + 0] = f.x;
                h[c*8 + d*2 + 1] = f.y;
            }
        }
    }
    for (int l = 0; l < 64; ++l) {
        float a0 = b1L[l], a1 = 0.f;
        #pragma unroll
        for (int j = 0; j < 128; j += 4) {
            const float4 wv = *(const float4*)&W1L[l*128 + j];
            a0 = fmaf(wv.x, h[j+0], a0);
            a1 = fmaf(wv.y, h[j+1], a1);
            a0 = fmaf(wv.z, h[j+2], a0);
            a1 = fmaf(wv.w, h[j+3], a1);
        }
        const float acc = a0 + a1;
        y1L[tid * 65 + l] = (acc > 0.f) ? acc : (__expf(acc) - 1.f);
    }
    float y30 = b3L[0], y31 = b3L[1];
    for (int l = 0; l < 64; ++l) {
        float a0 = b2L[l], a1 = 0.f;
        const int yb = tid * 65;
        #pragma unroll
        for (int j = 0; j < 64; j += 4) {
            const float4 wv = *(const float4*)&W2L[l*64 + j];
            a0 = fmaf(wv.x, y1L[yb + j+0], a0);
            a1 = fmaf(wv.y, y1L[yb + j+1], a1);
            a0 = fmaf(wv.z, y1L[yb + j+2], a0);
            a1 = fmaf(wv.w, y1L[yb + j+3], a1);
        }
        const float acc = a0 + a1;
        const float v = (acc > 0.f) ? acc : (__expf(acc) - 1.f);
        y30 = fmaf(W3L[l],      v, y30);
        y31 = fmaf(W3L[64 + l], v, y31);
    }
    out[row]            = y30;
    out[4 * TLEN + row] = y31;
}

extern "C" void kernel_launch(void* const* d_in, const int* in_sizes, int n_in,
                              void* d_out, int out_size, void* d_ws, size_t ws_size,
                              hipStream_t stream) {
    const float* px   = (const float*)d_in[0];
    const float* py   = (const float*)d_in[1];
    const float* vx   = (const float*)d_in[2];
    const float* vy   = (const float*)d_in[3];
    const float* Wemb = (const float*)d_in[4];
    const float* bemb = (const float*)d_in[5];
    const float* Wih  = (const float*)d_in[6];
    const float* Whh  = (const float*)d_in[7];
    const float* bih  = (const float*)d_in[8];
    const float* bhh  = (const float*)d_in[9];
    const float* W1   = (const float*)d_in[10];
    const float* b1   = (const float*)d_in[11];
    const float* W2   = (const float*)d_in[12];
    const float* b2   = (const float*)d_in[13];
    const float* W3   = (const float*)d_in[14];
    const float* b3   = (const float*)d_in[15];
    const int* step_mask = (const int*)d_in[16];
    const int* ctx       = (const int*)d_in[17];
    unsigned short* hs = (unsigned short*)d_ws;  // 4*16384*128 f16-bits = 16.8 MB
    float* out = (float*)d_out;                  // f32, [2][4][16384] flat

    hipLaunchKernelGGL(gru_kernel, dim3(1), dim3(768), 0, stream,
                       px, py, vx, vy, Wemb, bemb, Wih, Whh, bih, bhh,
                       step_mask, ctx, hs);
    hipLaunchKernelGGL(head_kernel, dim3(1024), dim3(64), 0, stream,
                       W1, b1, W2, b2, W3, b3, (const __half*)hs, out);
}

// Round 15
// 11404.099 us; speedup vs baseline: 2.6059x; 2.6059x over previous
//
#include <hip/hip_runtime.h>
#include <hip/hip_fp16.h>

#define TLEN 16384
#define HD 128

typedef _Float16 v8h __attribute__((ext_vector_type(8)));
typedef float    v4f __attribute__((ext_vector_type(4)));

union U4H8 { uint4 u; v8h h; };

__device__ __forceinline__ v8h cvt8(const float* p) {
    v8h r;
    #pragma unroll
    for (int i = 0; i < 8; ++i) r[i] = (_Float16)p[i];
    return r;
}
__device__ __forceinline__ unsigned int packh2(float a, float b) {
    union { _Float16 h[2]; unsigned int u; } c;
    c.h[0] = (_Float16)a; c.h[1] = (_Float16)b; return c.u;
}
__device__ __forceinline__ float selg(v4f a, int g) {
    const float lo = (g & 1) ? a.y : a.x;
    const float hi = (g & 1) ? a.w : a.z;
    return (g & 2) ? hi : lo;
}
#define PINA(x) asm volatile("" : "+a"(x))

// ---------------------------------------------------------------------------
// R15 = R12 (proven 11.1ms; the ONLY register-feasible shape: 512 thr/8
// waves = 256 regs/wave for 128 VGPR + 108 pinned AGPR) + single unified
// 32-slot h ring (write slot t&31, read slot (t-1)&31) => ONE ds_write per
// lane per step instead of two.  R13 (1024thr) and R14 (768thr) both broke
// the budget (64/84-reg grants) and spilled the A-frags — wave-count is
// pinned at 8.  Flush alternates wave-groups per 16-step half to balance.
// ---------------------------------------------------------------------------
__global__
__attribute__((amdgpu_flat_work_group_size(512, 512)))
void gru_kernel(
    const float* __restrict__ px,
    const float* __restrict__ py,
    const float* __restrict__ vx,
    const float* __restrict__ vy,
    const float* __restrict__ Wemb,   // [128,4]
    const float* __restrict__ bemb,   // [128]
    const float* __restrict__ Wih,    // [384,128]
    const float* __restrict__ Whh,    // [384,128]
    const float* __restrict__ bih,    // [384]
    const float* __restrict__ bhh,    // [384]
    const int*   __restrict__ step_mask, // [16384]
    const int*   __restrict__ ctxp,      // [1]
    unsigned short* __restrict__ hs)     // [4*16384*128] f16-bits staging
{
    const int tid  = threadIdx.x;
    const int w    = tid >> 6;          // wave 0..7 -> gate-rows 16w..16w+15
    const int lane = tid & 63;
    const int m    = lane & 15;
    const int q8   = (lane >> 4) * 8;
    const int qq4  = (lane >> 4) * 4;
    const int cme  = lane & 3;
    const int gme  = (lane >> 2) & 3;
    const int kme  = 16 * w + qq4 + gme;

    // unified h ring: slot t&31 holds h AFTER step t (f16, padded c-stride)
    __shared__ alignas(16) _Float16 ringL[32][4][160];
    __shared__ alignas(16) uint4 xpadL[256][4];          // [x0..x3,1,0,0,0] f16
    __shared__ int   uxbuf[256];
    __shared__ float WembL[512];
    __shared__ float bembL[128];
    __shared__ alignas(16) float Wc4[384][4];
    __shared__ float bfoldL[384];                        // Wih·bemb (no bih)

    // ---- A-frags: 6 tiles x 4 K-frags, AGPR-pinned ----
    v8h ahr0, ahr1, ahr2, ahr3, ahz0, ahz1, ahz2, ahz3, ahn0, ahn1, ahn2, ahn3;
    v8h air0, air1, air2, air3, aiz0, aiz1, aiz2, aiz3, ain0, ain1, ain2, ain3;
    {
        const float* pr = Whh + (size_t)(      16 * w + m) * 128 + q8;
        const float* pz = Whh + (size_t)(128 + 16 * w + m) * 128 + q8;
        const float* pn = Whh + (size_t)(256 + 16 * w + m) * 128 + q8;
        ahr0 = cvt8(pr); ahr1 = cvt8(pr + 32); ahr2 = cvt8(pr + 64); ahr3 = cvt8(pr + 96);
        ahz0 = cvt8(pz); ahz1 = cvt8(pz + 32); ahz2 = cvt8(pz + 64); ahz3 = cvt8(pz + 96);
        ahn0 = cvt8(pn); ahn1 = cvt8(pn + 32); ahn2 = cvt8(pn + 64); ahn3 = cvt8(pn + 96);
        const float* qr = Wih + (size_t)(      16 * w + m) * 128 + q8;
        const float* qz = Wih + (size_t)(128 + 16 * w + m) * 128 + q8;
        const float* qn = Wih + (size_t)(256 + 16 * w + m) * 128 + q8;
        air0 = cvt8(qr); air1 = cvt8(qr + 32); air2 = cvt8(qr + 64); air3 = cvt8(qr + 96);
        aiz0 = cvt8(qz); aiz1 = cvt8(qz + 32); aiz2 = cvt8(qz + 64); aiz3 = cvt8(qz + 96);
        ain0 = cvt8(qn); ain1 = cvt8(qn + 32); ain2 = cvt8(qn + 64); ain3 = cvt8(qn + 96);
    }
    PINA(ahr0); PINA(ahr1); PINA(ahr2); PINA(ahr3);
    PINA(ahz0); PINA(ahz1); PINA(ahz2); PINA(ahz3);
    PINA(ahn0); PINA(ahn1); PINA(ahn2); PINA(ahn3);
    PINA(air0); PINA(air1); PINA(air2); PINA(air3);
    PINA(aiz0); PINA(aiz1); PINA(aiz2); PINA(aiz3);
    PINA(ain0); PINA(ain1); PINA(ain2); PINA(ain3);

    // biases as MFMA C-init
    const int rB = 16 * w + qq4;
    const v4f bHR = { bhh[rB],       bhh[rB + 1],       bhh[rB + 2],       bhh[rB + 3] };
    const v4f bHZ = { bhh[128 + rB], bhh[128 + rB + 1], bhh[128 + rB + 2], bhh[128 + rB + 3] };
    const v4f bHN = { bhh[256 + rB], bhh[256 + rB + 1], bhh[256 + rB + 2], bhh[256 + rB + 3] };
    const v4f bIR = { bih[rB],       bih[rB + 1],       bih[rB + 2],       bih[rB + 3] };
    const v4f bIZ = { bih[128 + rB], bih[128 + rB + 1], bih[128 + rB + 2], bih[128 + rB + 3] };
    const v4f bIN = { bih[256 + rB], bih[256 + rB + 1], bih[256 + rB + 2], bih[256 + rB + 3] };

    if (tid < 512) WembL[tid] = Wemb[tid];
    if (tid < 128) bembL[tid] = bemb[tid];
    for (int i = tid; i < 32 * 4 * 160; i += 512) ((_Float16*)ringL)[i] = (_Float16)0.f;
    __syncthreads();
    // folded embed: Wc[g] = Wih[g]·Wemb, bfold[g] = Wih[g]·bemb  (NO bih)
    if (tid < 384) {
        const float* wr = Wih + (size_t)tid * 128;
        float c0 = 0.f, c1 = 0.f, c2 = 0.f, c3 = 0.f, cb = 0.f;
        #pragma unroll 4
        for (int j = 0; j < 128; ++j) {
            const float wv = wr[j];
            const float4 e = *(const float4*)&WembL[j * 4];
            c0 = fmaf(wv, e.x, c0); c1 = fmaf(wv, e.y, c1);
            c2 = fmaf(wv, e.z, c2); c3 = fmaf(wv, e.w, c3);
            cb = fmaf(wv, bembL[j], cb);
        }
        Wc4[tid][0] = c0; Wc4[tid][1] = c1; Wc4[tid][2] = c2; Wc4[tid][3] = c3;
        bfoldL[tid] = cb;
    }
    __syncthreads();
    // Wc A-frags: k=0..3 = Wc row, k=4 = bemb-fold, rest 0; lanes q8!=0 zero
    v8h wcr = {}, wcz = {}, wcn = {};
    if (lane < 16) {
        wcr[0] = (_Float16)Wc4[      16*w + m][0]; wcr[1] = (_Float16)Wc4[      16*w + m][1];
        wcr[2] = (_Float16)Wc4[      16*w + m][2]; wcr[3] = (_Float16)Wc4[      16*w + m][3];
        wcr[4] = (_Float16)bfoldL[      16*w + m];
        wcz[0] = (_Float16)Wc4[128 + 16*w + m][0]; wcz[1] = (_Float16)Wc4[128 + 16*w + m][1];
        wcz[2] = (_Float16)Wc4[128 + 16*w + m][2]; wcz[3] = (_Float16)Wc4[128 + 16*w + m][3];
        wcz[4] = (_Float16)bfoldL[128 + 16*w + m];
        wcn[0] = (_Float16)Wc4[256 + 16*w + m][0]; wcn[1] = (_Float16)Wc4[256 + 16*w + m][1];
        wcn[2] = (_Float16)Wc4[256 + 16*w + m][2]; wcn[3] = (_Float16)Wc4[256 + 16*w + m][3];
        wcn[4] = (_Float16)bfoldL[256 + 16*w + m];
    }
    PINA(wcr); PINA(wcz); PINA(wcn);

    const int ctxm = (ctxp[0] < 1) ? 1 : ctxp[0];
    float hold1 = 0.f;

    for (int t0 = 0; t0 < TLEN; t0 += 256) {
        // prefetch x (f16, 1.0 pad at k=4) + use_x flags
        for (int i = tid; i < 1024; i += 512) {
            const int t = i >> 2, c = i & 3;
            const int gt = t0 + t;
            const float* xa = (c == 0) ? px : (c == 1) ? py : (c == 2) ? vx : vy;
            uint4 u;
            u.x = packh2(xa[gt],            xa[TLEN + gt]);
            u.y = packh2(xa[2 * TLEN + gt], xa[3 * TLEN + gt]);
            u.z = packh2(1.f, 0.f);
            u.w = 0u;
            xpadL[t][c] = u;
        }
        if (tid < 256) {
            const int gt = t0 + tid;
            uxbuf[tid] = ((gt < ctxm) || (step_mask[gt] == 0)) ? 1 : 0;
        }
        __syncthreads();
        for (int tt = 0; tt < 256; ++tt) {
            const int gt = t0 + tt;
            // flush completed 16-step half (read-only; disjoint from current
            // writes); alternate wave-groups per group to balance skew.
            if ((gt & 15) == 1 && gt > 16) {
                const int G = (gt >> 4) - 1;
                const int inGrp = (G & 1) ? (tid >= 256) : (tid < 256);
                if (inGrp) {
                    const int u = tid & 255;
                    #pragma unroll
                    for (int j = 0; j < 4; ++j) {
                        const int v  = u + (j << 8);
                        const int c  = v >> 8, sl = (v >> 4) & 15, g = v & 15;
                        ((uint4*)hs)[(size_t)(c * TLEN + (G << 4) + sl) * 16 + g] =
                            *(const uint4*)&ringL[((G & 1) << 4) + sl][c][g << 3];
                    }
                }
            }
            const int ux = __builtin_amdgcn_readfirstlane(uxbuf[tt]);
            // B-frags from ring slot (gt-1)&31 (h entering step gt)
            const uint4* hq = (const uint4*)&ringL[(gt + 31) & 31][cme][0];
            U4H8 b0, b1, b2, b3;
            b0.u = hq[ 0 + (lane >> 4)];
            b1.u = hq[ 4 + (lane >> 4)];
            b2.u = hq[ 8 + (lane >> 4)];
            b3.u = hq[12 + (lane >> 4)];
            v4f aHR = __builtin_amdgcn_mfma_f32_16x16x32_f16(ahr0, b0.h, bHR, 0, 0, 0);
            aHR     = __builtin_amdgcn_mfma_f32_16x16x32_f16(ahr1, b1.h, aHR, 0, 0, 0);
            aHR     = __builtin_amdgcn_mfma_f32_16x16x32_f16(ahr2, b2.h, aHR, 0, 0, 0);
            aHR     = __builtin_amdgcn_mfma_f32_16x16x32_f16(ahr3, b3.h, aHR, 0, 0, 0);
            v4f aHZ = __builtin_amdgcn_mfma_f32_16x16x32_f16(ahz0, b0.h, bHZ, 0, 0, 0);
            aHZ     = __builtin_amdgcn_mfma_f32_16x16x32_f16(ahz1, b1.h, aHZ, 0, 0, 0);
            aHZ     = __builtin_amdgcn_mfma_f32_16x16x32_f16(ahz2, b2.h, aHZ, 0, 0, 0);
            aHZ     = __builtin_amdgcn_mfma_f32_16x16x32_f16(ahz3, b3.h, aHZ, 0, 0, 0);
            v4f aHN = __builtin_amdgcn_mfma_f32_16x16x32_f16(ahn0, b0.h, bHN, 0, 0, 0);
            aHN     = __builtin_amdgcn_mfma_f32_16x16x32_f16(ahn1, b1.h, aHN, 0, 0, 0);
            aHN     = __builtin_amdgcn_mfma_f32_16x16x32_f16(ahn2, b2.h, aHN, 0, 0, 0);
            aHN     = __builtin_amdgcn_mfma_f32_16x16x32_f16(ahn3, b3.h, aHN, 0, 0, 0);
            v4f aIR, aIZ, aIN;
            if (!ux) {
                aIR = __builtin_amdgcn_mfma_f32_16x16x32_f16(air0, b0.h, bIR, 0, 0, 0);
                aIR = __builtin_amdgcn_mfma_f32_16x16x32_f16(air1, b1.h, aIR, 0, 0, 0);
                aIR = __builtin_amdgcn_mfma_f32_16x16x32_f16(air2, b2.h, aIR, 0, 0, 0);
                aIR = __builtin_amdgcn_mfma_f32_16x16x32_f16(air3, b3.h, aIR, 0, 0, 0);
                aIZ = __builtin_amdgcn_mfma_f32_16x16x32_f16(aiz0, b0.h, bIZ, 0, 0, 0);
                aIZ = __builtin_amdgcn_mfma_f32_16x16x32_f16(aiz1, b1.h, aIZ, 0, 0, 0);
                aIZ = __builtin_amdgcn_mfma_f32_16x16x32_f16(aiz2, b2.h, aIZ, 0, 0, 0);
                aIZ = __builtin_amdgcn_mfma_f32_16x16x32_f16(aiz3, b3.h, aIZ, 0, 0, 0);
                aIN = __builtin_amdgcn_mfma_f32_16x16x32_f16(ain0, b0.h, bIN, 0, 0, 0);
                aIN = __builtin_amdgcn_mfma_f32_16x16x32_f16(ain1, b1.h, aIN, 0, 0, 0);
                aIN = __builtin_amdgcn_mfma_f32_16x16x32_f16(ain2, b2.h, aIN, 0, 0, 0);
                aIN = __builtin_amdgcn_mfma_f32_16x16x32_f16(ain3, b3.h, aIN, 0, 0, 0);
            } else {
                U4H8 xb;
                xb.u = xpadL[tt][cme];
                if (lane >= 16) { xb.u.x = 0u; xb.u.y = 0u; xb.u.z = 0u; xb.u.w = 0u; }
                aIR = __builtin_amdgcn_mfma_f32_16x16x32_f16(wcr, xb.h, bIR, 0, 0, 0);
                aIZ = __builtin_amdgcn_mfma_f32_16x16x32_f16(wcz, xb.h, bIZ, 0, 0, 0);
                aIN = __builtin_amdgcn_mfma_f32_16x16x32_f16(wcn, xb.h, bIN, 0, 0, 0);
            }
            const float gir = selg(aIR, gme), ghr = selg(aHR, gme);
            const float giz = selg(aIZ, gme), ghz = selg(aHZ, gme);
            const float gin = selg(aIN, gme), ghn = selg(aHN, gme);
            const float r    = 1.f / (1.f + __expf(-(gir + ghr)));
            const float z    = 1.f / (1.f + __expf(-(giz + ghz)));
            const float npre = fmaf(r, ghn, gin);
            const float e2   = __expf(2.f * npre);
            const float n    = 1.f - 2.f / (e2 + 1.f);       // tanh
            const float hnew = fmaf(z, hold1 - n, n);        // (1-z)n + z h
            hold1 = hnew;
            ringL[gt & 31][cme][kme] = (_Float16)hnew;       // single write
            __syncthreads();
        }
    }
    // final flush: steps 16368..16383 (slots 16..31)
    if (tid < 256) {
        #pragma unroll
        for (int j = 0; j < 4; ++j) {
            const int v  = tid + (j << 8);
            const int c  = v >> 8, sl = (v >> 4) & 15, g = v & 15;
            ((uint4*)hs)[(size_t)(c * TLEN + 16368 + sl) * 16 + g] =
                *(const uint4*)&ringL[16 + sl][c][g << 3];
        }
    }
}

// ---------------------------------------------------------------------------
// Head MLP over all 65536 hidden states (unchanged).
// ---------------------------------------------------------------------------
__global__ __launch_bounds__(64) void head_kernel(
    const float*  __restrict__ W1,
    const float*  __restrict__ b1,
    const float*  __restrict__ W2,
    const float*  __restrict__ b2,
    const float*  __restrict__ W3,
    const float*  __restrict__ b3,
    const __half* __restrict__ hs,
    float*        __restrict__ out)
{
    __shared__ float W1L[64 * 128];
    __shared__ float W2L[64 * 64];
    __shared__ float W3L[2 * 64];
    __shared__ float b1L[64], b2L[64], b3L[2];
    __shared__ float y1L[64 * 65];

    const int tid = threadIdx.x;
    {
        float4* dst1 = (float4*)W1L; const float4* src1 = (const float4*)W1;
        for (int i = tid; i < 2048; i += 64) dst1[i] = src1[i];
        float4* dst2 = (float4*)W2L; const float4* src2 = (const float4*)W2;
        for (int i = tid; i < 1024; i += 64) dst2[i] = src2[i];
        if (tid < 32) ((float4*)W3L)[tid] = ((const float4*)W3)[tid];
        b1L[tid] = b1[tid];
        b2L[tid] = b2[tid];
        if (tid < 2) b3L[tid] = b3[tid];
    }
    __syncthreads();

    const int row = blockIdx.x * 64 + tid;
    float h[128];
    {
        const uint4* hp = (const uint4*)(hs + (size_t)row * HD);
        #pragma unroll
        for (int c = 0; c < 16; ++c) {
            uint4 q = hp[c];
            const __half2* hh = (const __half2*)&q;
            #pragma unroll
            for (int d = 0; d < 4; ++d) {
                const float2 f = __half22float2(hh[d]);
                h[c*8 + d*2 + 0] = f.x;
                h[c*8 + d*2 + 1] = f.y;
            }
        }
    }
    for (int l = 0; l < 64; ++l) {
        float a0 = b1L[l], a1 = 0.f;
        #pragma unroll
        for (int j = 0; j < 128; j += 4) {
            const float4 wv = *(const float4*)&W1L[l*128 + j];
            a0 = fmaf(wv.x, h[j+0], a0);
            a1 = fmaf(wv.y, h[j+1], a1);
            a0 = fmaf(wv.z, h[j+2], a0);
            a1 = fmaf(wv.w, h[j+3], a1);
        }
        const float acc = a0 + a1;
        y1L[tid * 65 + l] = (acc > 0.f) ? acc : (__expf(acc) - 1.f);
    }
    float y30 = b3L[0], y31 = b3L[1];
    for (int l = 0; l < 64; ++l) {
        float a0 = b2L[l], a1 = 0.f;
        const int yb = tid * 65;
        #pragma unroll
        for (int j = 0; j < 64; j += 4) {
            const float4 wv = *(const float4*)&W2L[l*64 + j];
            a0 = fmaf(wv.x, y1L[yb + j+0], a0);
            a1 = fmaf(wv.y, y1L[yb + j+1], a1);
            a0 = fmaf(wv.z, y1L[yb + j+2], a0);
            a1 = fmaf(wv.w, y1L[yb + j+3], a1);
        }
        const float acc = a0 + a1;
        const float v = (acc > 0.f) ? acc : (__expf(acc) - 1.f);
        y30 = fmaf(W3L[l],      v, y30);
        y31 = fmaf(W3L[64 + l], v, y31);
    }
    out[row]            = y30;
    out[4 * TLEN + row] = y31;
}

extern "C" void kernel_launch(void* const* d_in, const int* in_sizes, int n_in,
                              void* d_out, int out_size, void* d_ws, size_t ws_size,
                              hipStream_t stream) {
    const float* px   = (const float*)d_in[0];
    const float* py   = (const float*)d_in[1];
    const float* vx   = (const float*)d_in[2];
    const float* vy   = (const float*)d_in[3];
    const float* Wemb = (const float*)d_in[4];
    const float* bemb = (const float*)d_in[5];
    const float* Wih  = (const float*)d_in[6];
    const float* Whh  = (const float*)d_in[7];
    const float* bih  = (const float*)d_in[8];
    const float* bhh  = (const float*)d_in[9];
    const float* W1   = (const float*)d_in[10];
    const float* b1   = (const float*)d_in[11];
    const float* W2   = (const float*)d_in[12];
    const float* b2   = (const float*)d_in[13];
    const float* W3   = (const float*)d_in[14];
    const float* b3   = (const float*)d_in[15];
    const int* step_mask = (const int*)d_in[16];
    const int* ctx       = (const int*)d_in[17];
    unsigned short* hs = (unsigned short*)d_ws;  // 4*16384*128 f16-bits = 16.8 MB
    float* out = (float*)d_out;                  // f32, [2][4][16384] flat

    hipLaunchKernelGGL(gru_kernel, dim3(1), dim3(512), 0, stream,
                       px, py, vx, vy, Wemb, bemb, Wih, Whh, bih, bhh,
                       step_mask, ctx, hs);
    hipLaunchKernelGGL(head_kernel, dim3(1024), dim3(64), 0, stream,
                       W1, b1, W2, b2, W3, b3, (const __half*)hs, out);
}